// Round 2
// baseline (2511.642 us; speedup 1.0000x reference)
//
#include <hip/hip_runtime.h>

// ---------------- constants ----------------
#define NTOK  49          // tokens per window
#define NWTOT 4096        // BATCH*8*8 windows
#define TTOK  200704      // 64*56*56 tokens
#define HEADS 8

using bshort8 = __attribute__((ext_vector_type(8))) short;
using f32x4   = __attribute__((ext_vector_type(4))) float;

// ---------------- helpers ----------------
__device__ __forceinline__ float bfu2f(unsigned short u) {
    return __uint_as_float(((unsigned)u) << 16);
}
__device__ __forceinline__ unsigned short f2bfu(float f) {
    unsigned u = __float_as_uint(f);
    u = u + 0x7fffu + ((u >> 16) & 1u);   // round-to-nearest-even
    return (unsigned short)(u >> 16);
}
__device__ __forceinline__ float gelu_f(float x) {
    return 0.5f * x * (1.0f + erff(x * 0.70710678118654752f));
}

// ---------------- workspace byte offsets (total ~197.4 MB) ----------------
#define OFF_XW     0ull                          // bf16 T*256 (LN1 out, window layout; reused as MIX out)
#define OFF_XP     (OFF_XW   + 102760448ull)     // bf16 T*256 (pre-proj out; reused as XN2)
#define OFF_W1T    (OFF_XP   + 102760448ull)     // bf16 64x256
#define OFF_W2T    (OFF_W1T  + 32768ull)         // bf16 64x64
#define OFF_PREWT  (OFF_W2T  + 8192ull)          // bf16 256x256
#define OFF_POSTWT (OFF_PREWT+ 131072ull)        // bf16 256x256
#define OFF_FC1T   (OFF_POSTWT+131072ull)        // bf16 1024x256
#define OFF_FC2T   (OFF_FC1T + 524288ull)        // bf16 256x1024
#define OFF_WB     (OFF_FC2T + 524288ull)        // f32  8x49x49
// end = 206,949,408 bytes

// scratch carved out of d_out (dead before y1 is written there):
#define DOUT_HAD   0ull                          // bf16 T*64  (25,690,112 B)
#define DOUT_MP    25690112ull                   // bf16 T*64

// ---------------- prep: weight transpose->bf16 + rel-pos gather ----------------
__global__ __launch_bounds__(256) void prep_k(
    const float* __restrict__ w1, const float* __restrict__ w2,
    const float* __restrict__ prew, const float* __restrict__ postw,
    const float* __restrict__ fc1w, const float* __restrict__ fc2w,
    const float* __restrict__ wbank, const int* __restrict__ relidx,
    unsigned short* __restrict__ w1T, unsigned short* __restrict__ w2T,
    unsigned short* __restrict__ prewT, unsigned short* __restrict__ postwT,
    unsigned short* __restrict__ fc1T, unsigned short* __restrict__ fc2T,
    float* __restrict__ wb)
{
    int i = blockIdx.x * 256 + threadIdx.x;
    if (i < 64*256)   { int n = i >> 8,  k = i & 255;  w1T[i]   = f2bfu(w1[k*64 + n]); }
    if (i < 64*64)    { int n = i >> 6,  k = i & 63;   w2T[i]   = f2bfu(w2[k*64 + n]); }
    if (i < 256*256)  { int n = i >> 8,  k = i & 255;  prewT[i] = f2bfu(prew[k*256 + n]);
                                                       postwT[i]= f2bfu(postw[k*256 + n]); }
    if (i < 1024*256) { int n = i >> 8,  k = i & 255;  fc1T[i]  = f2bfu(fc1w[k*1024 + n]); }
    if (i < 256*1024) { int n = i >> 10, k = i & 1023; fc2T[i]  = f2bfu(fc2w[k*256 + n]); }
    if (i < 8*NTOK*NTOK) { int k = i / 2401, nm = i - k*2401; wb[i] = wbank[k*169 + relidx[nm]]; }
}

// ---------------- LayerNorm (one wave per token), optional window-partition remap ----------------
template<bool REMAP>
__global__ __launch_bounds__(256) void ln_k(
    const float* __restrict__ x, const float* __restrict__ sc,
    const float* __restrict__ bs, unsigned short* __restrict__ out)
{
    const int lane = threadIdx.x & 63;
    const long t = (long)blockIdx.x * 4 + (threadIdx.x >> 6);
    const float4 v = ((const float4*)(x + t * 256))[lane];
    float s = v.x + v.y + v.z + v.w;
    #pragma unroll
    for (int o = 32; o; o >>= 1) s += __shfl_xor(s, o);
    const float mu = s * 0.00390625f;
    const float dx = v.x - mu, dy = v.y - mu, dz = v.z - mu, dw = v.w - mu;
    float q = dx*dx + dy*dy + dz*dz + dw*dw;
    #pragma unroll
    for (int o = 32; o; o >>= 1) q += __shfl_xor(q, o);
    const float rstd = rsqrtf(q * 0.00390625f + 1e-5f);
    const float4 s4 = ((const float4*)sc)[lane];
    const float4 b4 = ((const float4*)bs)[lane];
    long dt;
    if (REMAP) {
        int ti = (int)t, bi = ti / 3136, rem = ti - bi * 3136;
        int hh = rem / 56, ww = rem - hh * 56;
        dt = (long)(bi*64 + (hh/7)*8 + (ww/7)) * NTOK + (hh%7)*7 + (ww%7);
    } else dt = t;
    ushort4 o4;
    o4.x = f2bfu(dx*rstd*s4.x + b4.x);
    o4.y = f2bfu(dy*rstd*s4.y + b4.y);
    o4.z = f2bfu(dz*rstd*s4.z + b4.z);
    o4.w = f2bfu(dw*rstd*s4.w + b4.w);
    ((ushort4*)(out + dt * 256))[lane] = o4;
}

// ---------------- generic MFMA GEMM: C[M,N] = A[M,K] @ Bt[N,K]^T + bias ----------------
// EPI: 0 = store bf16; 1 = GELU, store bf16;
//      3 = window-reverse + residual (outf = res + gamma*val), N must be 256.
template<int EPI>
__global__ __launch_bounds__(256) void gemm_k(
    const unsigned short* __restrict__ A, const unsigned short* __restrict__ Bt,
    const float* __restrict__ bias, int Nn, int K,
    unsigned short* __restrict__ outb, float* __restrict__ outf,
    const float* __restrict__ res, const float* __restrict__ gamma)
{
    const int lane = threadIdx.x & 63;
    const int wave = threadIdx.x >> 6;
    const int wm = wave >> 1, wn = wave & 1;
    const int lrow = lane & 15, kgrp = lane >> 4;
    const long m0 = (long)blockIdx.x * 64;
    const unsigned short* Ap = A + (m0 + wm*32 + lrow) * (long)K + kgrp*8;
    const int ntiles = Nn >> 6;
    for (int bn = 0; bn < ntiles; ++bn) {
        const unsigned short* Bp = Bt + (long)(bn*64 + wn*32 + lrow) * K + kgrp*8;
        f32x4 acc00 = {0,0,0,0}, acc01 = {0,0,0,0}, acc10 = {0,0,0,0}, acc11 = {0,0,0,0};
        for (int k0 = 0; k0 < K; k0 += 32) {
            bshort8 a0 = *(const bshort8*)(Ap + k0);
            bshort8 a1 = *(const bshort8*)(Ap + (long)16*K + k0);
            bshort8 b0 = *(const bshort8*)(Bp + k0);
            bshort8 b1 = *(const bshort8*)(Bp + (long)16*K + k0);
            acc00 = __builtin_amdgcn_mfma_f32_16x16x32_bf16(a0, b0, acc00, 0, 0, 0);
            acc01 = __builtin_amdgcn_mfma_f32_16x16x32_bf16(a0, b1, acc01, 0, 0, 0);
            acc10 = __builtin_amdgcn_mfma_f32_16x16x32_bf16(a1, b0, acc10, 0, 0, 0);
            acc11 = __builtin_amdgcn_mfma_f32_16x16x32_bf16(a1, b1, acc11, 0, 0, 0);
        }
        #pragma unroll
        for (int i = 0; i < 2; ++i) {
            #pragma unroll
            for (int j = 0; j < 2; ++j) {
                f32x4 v = (i == 0) ? (j == 0 ? acc00 : acc01) : (j == 0 ? acc10 : acc11);
                const int col = bn*64 + wn*32 + j*16 + lrow;
                const float bc = bias[col];
                #pragma unroll
                for (int r = 0; r < 4; ++r) {
                    const long row = m0 + wm*32 + i*16 + kgrp*4 + r;
                    float val = v[r] + bc;
                    if constexpr (EPI == 0) {
                        outb[row * Nn + col] = f2bfu(val);
                    } else if constexpr (EPI == 1) {
                        outb[row * Nn + col] = f2bfu(gelu_f(val));
                    } else { // EPI == 3
                        int t = (int)row; int win = t / NTOK, n = t - win * NTOK;
                        int bi = win >> 6, wh = (win >> 3) & 7, ww = win & 7;
                        int hh = wh*7 + n/7, wc = ww*7 + n%7;
                        long o = (long)((bi*56 + hh)*56 + wc) * 256 + col;
                        outf[o] = res[o] + gamma[col] * val;
                    }
                }
            }
        }
    }
}

// ---------------- fused MLP: y += gamma2 * (gelu(xn2@fc1+b1)@fc2 + b2), in-place on y ----------------
__global__ __launch_bounds__(256) void mlp_k(
    const unsigned short* __restrict__ xn2,   // (T,256) bf16
    const unsigned short* __restrict__ fc1T,  // (1024,256) [n][k] bf16
    const float* __restrict__ fc1b,
    const unsigned short* __restrict__ fc2T,  // (256,1024) [n][k] bf16
    const float* __restrict__ fc2b,
    const float* __restrict__ gamma2,
    float* __restrict__ y)                    // (T,256) f32, read-modify-write
{
    __shared__ unsigned short a_s[64 * 256];  // 32 KB, XOR-swizzled 16B blocks
    __shared__ unsigned short h_s[64 * 64];   // 8 KB, XOR-swizzled 16B blocks
    const int tid  = threadIdx.x;
    const int lane = tid & 63, wave = tid >> 6;
    const int lrow = lane & 15, kgrp = lane >> 4;
    const long m0 = (long)blockIdx.x * 64;

    // stage A tile (swizzle: 16B-block index ^= row&7)
    #pragma unroll
    for (int it = 0; it < 8; ++it) {
        int idx = it * 256 + tid;           // 0..2047 16B units
        int row = idx >> 5, cb = idx & 31;
        bshort8 v = *(const bshort8*)(xn2 + (m0 + row) * 256 + cb * 8);
        *(bshort8*)(a_s + row * 256 + ((cb ^ (row & 7)) * 8)) = v;
    }

    f32x4 oacc[4][4];
    #pragma unroll
    for (int i = 0; i < 4; ++i)
        #pragma unroll
        for (int j = 0; j < 4; ++j) oacc[i][j] = (f32x4){0,0,0,0};

    __syncthreads();

    const int arow = wave * 16 + lrow;       // this wave's A-row for phase A
    const int abase = arow * 256;
    const int asw = arow & 7;

    for (int chunk = 0; chunk < 16; ++chunk) {
        // ---- phase A: h[arow][0..63] = gelu(a[arow][:] @ fc1_chunk^T + b1)
        bshort8 af[8];
        #pragma unroll
        for (int ks = 0; ks < 8; ++ks)
            af[ks] = *(const bshort8*)(a_s + abase + (((ks * 4 + kgrp) ^ asw) * 8));
        f32x4 hacc[4];
        #pragma unroll
        for (int cb = 0; cb < 4; ++cb) hacc[cb] = (f32x4){0,0,0,0};
        #pragma unroll
        for (int cb = 0; cb < 4; ++cb) {
            #pragma unroll
            for (int ks = 0; ks < 8; ++ks) {
                bshort8 bf = *(const bshort8*)(fc1T + (chunk*64 + cb*16 + lrow) * 256 + ks*32 + kgrp*8);
                hacc[cb] = __builtin_amdgcn_mfma_f32_16x16x32_bf16(af[ks], bf, hacc[cb], 0, 0, 0);
            }
        }
        __syncthreads();   // previous chunk's phase-B reads of h_s are done
        #pragma unroll
        for (int cb = 0; cb < 4; ++cb) {
            const int hcol = cb * 16 + lrow;
            const float bia = fc1b[chunk * 64 + hcol];
            #pragma unroll
            for (int r = 0; r < 4; ++r) {
                int hrow = wave * 16 + kgrp * 4 + r;
                float v = gelu_f(hacc[cb][r] + bia);
                h_s[hrow * 64 + (((hcol >> 3) ^ (hrow & 7)) * 8) + (hcol & 7)] = f2bfu(v);
            }
        }
        __syncthreads();
        // ---- phase B: oacc[64 x 64-col-slice] += h @ fc2_chunk^T
        #pragma unroll
        for (int ks = 0; ks < 2; ++ks) {
            bshort8 ha[4];
            #pragma unroll
            for (int mb = 0; mb < 4; ++mb) {
                int hrow = mb * 16 + lrow;
                ha[mb] = *(const bshort8*)(h_s + hrow * 64 + (((ks * 4 + kgrp) ^ (hrow & 7)) * 8));
            }
            #pragma unroll
            for (int nb = 0; nb < 4; ++nb) {
                bshort8 hb = *(const bshort8*)(fc2T + (long)(wave*64 + nb*16 + lrow) * 1024 + chunk*64 + ks*32 + kgrp*8);
                #pragma unroll
                for (int mb = 0; mb < 4; ++mb)
                    oacc[mb][nb] = __builtin_amdgcn_mfma_f32_16x16x32_bf16(ha[mb], hb, oacc[mb][nb], 0, 0, 0);
            }
        }
    }
    // epilogue: y += gamma2 * (oacc + fc2b)
    #pragma unroll
    for (int nb = 0; nb < 4; ++nb) {
        const int col = wave * 64 + nb * 16 + lrow;
        const float b2 = fc2b[col], g2 = gamma2[col];
        #pragma unroll
        for (int mb = 0; mb < 4; ++mb) {
            #pragma unroll
            for (int r = 0; r < 4; ++r) {
                long row = m0 + mb * 16 + kgrp * 4 + r;
                long o = row * 256 + col;
                y[o] = y[o] + g2 * (oacc[mb][nb][r] + b2);
            }
        }
    }
}

// ---------------- per-window adaptive mix ----------------
// mp: (T,64) bf16 [n,k,h]; wb: (8,49,49) f32 [k,n,m]; xp: (T,256) bf16; mix out bf16
__global__ __launch_bounds__(512) void mix_k(
    const unsigned short* __restrict__ mp, const float* __restrict__ wb,
    const unsigned short* __restrict__ xp, unsigned short* __restrict__ mix)
{
    __shared__ unsigned short xh_s[NTOK * 256];          // 25.1 KB bf16
    __shared__ unsigned short P_s[NTOK * NTOK * HEADS];  // 38.4 KB
    const int tid = threadIdx.x;
    const long win = blockIdx.x;
    const unsigned short* mpg = mp + win * (NTOK * 64);
    const unsigned short* xpg = xp + win * (NTOK * 256);
    for (int i = tid; i < NTOK * 16; i += 512)           // 784 x 16B
        ((uint4*)xh_s)[i] = ((const uint4*)xpg)[i];
    __syncthreads();
    // phase 1: w[n,m,h] = sum_k mp[n,k,h]*wb[k,n,m]; softmax over n; store bf16
    if (tid < NTOK * HEADS) {
        const int m = tid % NTOK, h = tid / NTOK;
        float col[NTOK];
        float mx = -1e30f;
        #pragma unroll
        for (int n = 0; n < NTOK; ++n) {
            float acc = 0.f;
            #pragma unroll
            for (int k = 0; k < 8; ++k)
                acc += bfu2f(mpg[n*64 + k*8 + h]) * wb[k*2401 + n*49 + m];
            col[n] = acc; mx = fmaxf(mx, acc);
        }
        float ssum = 0.f;
        #pragma unroll
        for (int n = 0; n < NTOK; ++n) { float e = __expf(col[n] - mx); col[n] = e; ssum += e; }
        const float rinv = 1.0f / ssum;
        #pragma unroll
        for (int n = 0; n < NTOK; ++n)
            P_s[n*392 + m*8 + h] = f2bfu(col[n] * rinv);
    }
    __syncthreads();
    // phase 2: out[m, h*32+c] = sum_n P[n,m,h] * xh[n, h*32+c]
    unsigned short* mo = mix + win * (NTOK * 256);
    for (int item = tid; item < NTOK * HEADS * 4; item += 512) {
        const int cg = item & 3, mh = item >> 2;
        const int h = mh & 7, m = mh >> 3;
        const int cbase = h*32 + cg*8;
        float a0=0,a1=0,a2=0,a3=0,a4=0,a5=0,a6=0,a7=0;
        for (int n = 0; n < NTOK; ++n) {
            const float p = bfu2f(P_s[n*392 + m*8 + h]);
            const unsigned short* xr = &xh_s[n*256 + cbase];
            a0 += p*bfu2f(xr[0]); a1 += p*bfu2f(xr[1]); a2 += p*bfu2f(xr[2]); a3 += p*bfu2f(xr[3]);
            a4 += p*bfu2f(xr[4]); a5 += p*bfu2f(xr[5]); a6 += p*bfu2f(xr[6]); a7 += p*bfu2f(xr[7]);
        }
        ushort4 q0, q1;
        q0.x=f2bfu(a0); q0.y=f2bfu(a1); q0.z=f2bfu(a2); q0.w=f2bfu(a3);
        q1.x=f2bfu(a4); q1.y=f2bfu(a5); q1.z=f2bfu(a6); q1.w=f2bfu(a7);
        ((ushort4*)(mo + m*256 + cbase))[0] = q0;
        ((ushort4*)(mo + m*256 + cbase))[1] = q1;
    }
}

// ---------------- launch ----------------
extern "C" void kernel_launch(void* const* d_in, const int* in_sizes, int n_in,
                              void* d_out, int out_size, void* d_ws, size_t ws_size,
                              hipStream_t stream) {
    const float* x         = (const float*)d_in[0];
    const float* norm1_s   = (const float*)d_in[1];
    const float* norm1_b   = (const float*)d_in[2];
    const float* gamma1    = (const float*)d_in[3];
    const float* aw1       = (const float*)d_in[4];
    const float* ab1       = (const float*)d_in[5];
    const float* aw2       = (const float*)d_in[6];
    const float* ab2       = (const float*)d_in[7];
    const float* wbank     = (const float*)d_in[8];
    const float* pre_w     = (const float*)d_in[9];
    const float* pre_b     = (const float*)d_in[10];
    const float* post_w    = (const float*)d_in[11];
    const float* post_b    = (const float*)d_in[12];
    const float* norm2_s   = (const float*)d_in[13];
    const float* norm2_b   = (const float*)d_in[14];
    const float* gamma2    = (const float*)d_in[15];
    const float* fc1_w     = (const float*)d_in[16];
    const float* fc1_b     = (const float*)d_in[17];
    const float* fc2_w     = (const float*)d_in[18];
    const float* fc2_b     = (const float*)d_in[19];
    const int*   rel_idx   = (const int*)d_in[20];

    char* ws = (char*)d_ws;
    unsigned short* xw    = (unsigned short*)(ws + OFF_XW);    // also MIX out
    unsigned short* xp    = (unsigned short*)(ws + OFF_XP);    // also XN2
    unsigned short* w1T   = (unsigned short*)(ws + OFF_W1T);
    unsigned short* w2T   = (unsigned short*)(ws + OFF_W2T);
    unsigned short* prewT = (unsigned short*)(ws + OFF_PREWT);
    unsigned short* postwT= (unsigned short*)(ws + OFF_POSTWT);
    unsigned short* fc1T  = (unsigned short*)(ws + OFF_FC1T);
    unsigned short* fc2T  = (unsigned short*)(ws + OFF_FC2T);
    float*          wb    = (float*)(ws + OFF_WB);

    // scratch inside d_out (dead before y1 is produced there)
    unsigned short* had = (unsigned short*)((char*)d_out + DOUT_HAD);
    unsigned short* mp  = (unsigned short*)((char*)d_out + DOUT_MP);
    float*          y   = (float*)d_out;

    const int GB = TTOK / 64;   // 3136 tiles of 64 rows

    prep_k<<<1024, 256, 0, stream>>>(aw1, aw2, pre_w, post_w, fc1_w, fc2_w, wbank, rel_idx,
                                     w1T, w2T, prewT, postwT, fc1T, fc2T, wb);
    ln_k<true><<<TTOK/4, 256, 0, stream>>>(x, norm1_s, norm1_b, xw);
    gemm_k<1><<<GB, 256, 0, stream>>>(xw, w1T, ab1, 64, 256, had, nullptr, nullptr, nullptr);
    gemm_k<0><<<GB, 256, 0, stream>>>(had, w2T, ab2, 64, 64, mp, nullptr, nullptr, nullptr);
    gemm_k<0><<<GB, 256, 0, stream>>>(xw, prewT, pre_b, 256, 256, xp, nullptr, nullptr, nullptr);
    mix_k<<<NWTOT, 512, 0, stream>>>(mp, wb, xp, xw);
    gemm_k<3><<<GB, 256, 0, stream>>>(xw, postwT, post_b, 256, 256, nullptr, y, x, gamma1);
    ln_k<false><<<TTOK/4, 256, 0, stream>>>(y, norm2_s, norm2_b, xp);
    mlp_k<<<GB, 256, 0, stream>>>(xp, fc1T, fc1_b, fc2T, fc2_b, gamma2, y);
}